// Round 1
// baseline (565.521 us; speedup 1.0000x reference)
//
#include <hip/hip_runtime.h>
#include <stdint.h>

typedef unsigned short u16;
typedef short bf16x8 __attribute__((ext_vector_type(8)));
typedef float f32x4 __attribute__((ext_vector_type(4)));
typedef u16 u16x4 __attribute__((ext_vector_type(4)));

__device__ __forceinline__ u16 f2bf(float f) {
    union { float f; unsigned int i; } v; v.f = f;
    unsigned int x = v.i;
    return (u16)((x + 0x7FFFu + ((x >> 16) & 1u)) >> 16);  // RNE
}

// Async global->LDS, 16B per lane. LDS dest is wave-uniform base; HW adds lane*16.
__device__ __forceinline__ void async_load16(const u16* g, u16* lds) {
    __builtin_amdgcn_global_load_lds(
        (const __attribute__((address_space(1))) unsigned int*)g,
        (__attribute__((address_space(3))) unsigned int*)lds,
        16, 0, 0);
}

// ---------------------------------------------------------------------------
// Gt[col][row] (4096 x 4096 bf16) from f32 BTT cores. (unchanged, verified)
// ---------------------------------------------------------------------------
__global__ void build_gt(const float* __restrict__ c0, const float* __restrict__ c1,
                         const float* __restrict__ c2, u16* __restrict__ Gt) {
    const int y1  = blockIdx.x >> 4;
    const int x1  = blockIdx.x & 15;
    const int r   = blockIdx.y * 256 + threadIdx.x;

    float a0[8];
    {
        f32x4 v0 = *(const f32x4*)(c0 + ((size_t)r * 16 + y1) * 8);
        f32x4 v1 = *(const f32x4*)(c0 + ((size_t)r * 16 + y1) * 8 + 4);
        #pragma unroll
        for (int b = 0; b < 4; ++b) { a0[b] = v0[b]; a0[4 + b] = v1[b]; }
    }
    float t[8];
    const float* c1row = c1 + ((size_t)r * 16 + x1) * 64;
    #pragma unroll
    for (int c = 0; c < 8; ++c) {
        f32x4 v0 = *(const f32x4*)(c1row + c * 8);
        f32x4 v1 = *(const f32x4*)(c1row + c * 8 + 4);
        float s = 0.f;
        #pragma unroll
        for (int b = 0; b < 4; ++b) s += v0[b] * a0[b] + v1[b] * a0[4 + b];
        t[c] = s;
    }
    const float* c2row = c2 + (size_t)r * 128;
    #pragma unroll
    for (int x2 = 0; x2 < 16; ++x2) {
        f32x4 v0 = *(const f32x4*)(c2row + x2 * 8);
        f32x4 v1 = *(const f32x4*)(c2row + x2 * 8 + 4);
        float s = 0.f;
        #pragma unroll
        for (int c = 0; c < 4; ++c) s += v0[c] * t[c] + v1[c] * t[4 + c];
        Gt[((size_t)(blockIdx.x * 16 + x2)) * 4096 + r] = f2bf(s);
    }
}

// X: f32 -> bf16, vectorized. (unchanged, verified)
__global__ void conv_x(const f32x4* __restrict__ x, u16* __restrict__ xb, int n4) {
    for (int i = blockIdx.x * 256 + threadIdx.x; i < n4; i += gridDim.x * 256) {
        f32x4 v = x[i];
        u16x4 o;
        #pragma unroll
        for (int j = 0; j < 4; ++j) o[j] = f2bf(v[j]);
        *(u16x4*)(xb + 4 * (size_t)i) = o;
    }
}

// ---------------------------------------------------------------------------
// 256x256 8-phase GEMM (m201-style T2+T3+T4+T5), C = X(bf16) @ Gt^T + bias.
// M=8192, N=K=4096. 512 threads = 8 waves (2M x 4N), per-wave out 128x64.
// LDS 128KiB: 2 dbuf x { A[2 half][128x64] , B[2 half][128x64] } bf16.
//
// Interleaved frag mapping: wave (wmi,wni); m-frag i -> rows (2i+wmi)*16,
// n-frag j -> rows (4j+wni)*16.  Phase quadrant (mh,nh) therefore touches
// exactly A-half mh and B-half nh => halves are PHASE-freed:
//   A-h0 free after ph1, B-h0 after ph3 (re-read), A-h1 after ph3(regs to ph4),
//   B-h1 after ph4.
// Prefetch per phase (1 half-tile = 2 global_load_lds/thread):
//   ph1: (T+1)A-h1 -> other buf   ph2: (T+1)B-h1 -> other buf
//   ph3: (T+2)A-h0 -> this buf    ph4: (T+2)B-h0 -> this buf
// Counted waits (FIFO-derived, never 0 in loop): vmcnt(6) end ph1 (covers
// next ph2/ph3 reads), vmcnt(8) end ph4 (covers next group's ph1 reads).
// Tail: source tile index clamped (&63); dummy loads land in freed slots.
//
// XOR swizzle (row&7 on 16B-slot index) applied on BOTH sides:
// inverse-swizzled global source for global_load_lds (linear LDS dest) +
// swizzled ds_read addr => 8 lanes per 16B slot = conflict-free b128 reads.
// ---------------------------------------------------------------------------
__global__ __launch_bounds__(512, 2)
void gemm_8ph(const u16* __restrict__ Xb, const u16* __restrict__ Gt,
              const float* __restrict__ bias, float* __restrict__ out) {
    constexpr int K = 4096, N = 4096, NT = 64;
    extern __shared__ u16 lds[];  // 65536 u16 = 128 KiB

    const int tid  = threadIdx.x;
    const int lane = tid & 63;
    const int w    = tid >> 6;
    const int wmi  = w >> 2;       // 0..1
    const int wni  = w & 3;        // 0..3
    const int lr   = lane & 15;
    const int lq   = lane >> 4;    // 0..3
    const int xr   = lr & 7;       // xor bits for swizzle

    const int m0 = blockIdx.y * 256;
    const int n0 = blockIdx.x * 256;

    // --- staging maps (2 issues per thread per half-tile of 128x64 bf16) ---
    const int r0 = tid >> 3;                 // 0..63
    const int s0 = (tid & 7) ^ (r0 & 7);     // inverse-swizzled slot
    const int r1 = 64 + r0;                  // issue 1
    const int s1 = ((512 + tid) & 7) ^ (r1 & 7);
    const size_t aoff0 = (size_t)(m0 + r0) * K + s0 * 8;
    const size_t aoff1 = (size_t)(m0 + r1) * K + s1 * 8;
    const size_t boff0 = (size_t)(n0 + r0) * K + s0 * 8;
    const size_t boff1 = (size_t)(n0 + r1) * K + s1 * 8;
    const int ldsw0 = (tid & ~63) * 8;           // wave-uniform LDS base, issue 0
    const int ldsw1 = 4096 + (tid & ~63) * 8;    // issue 1

    // --- ds_read bases (u16 units). Region: A at 0, B at 16384; half*8192. ---
    const int aoffL = (wmi * 16 + lr) * 64;
    const int boffL = 16384 + (wni * 16 + lr) * 64;
    const int slot0 = (lq ^ xr) * 8;            // kk=0 swizzled 16B slot
    const int slot1 = ((4 + lq) ^ xr) * 8;      // kk=1

    f32x4 acc[8][4] = {};
    bf16x8 a[4][2], b2[2][2];

    auto stageA = [&](int b, int h, int t) {
        const u16* s = Xb + (size_t)h * (128 * K) + (size_t)t * 64;
        u16* d = lds + b * 32768 + h * 8192;
        async_load16(s + aoff0, d + ldsw0);
        async_load16(s + aoff1, d + ldsw1);
    };
    auto stageB = [&](int b, int h, int t) {
        const u16* s = Gt + (size_t)h * (128 * K) + (size_t)t * 64;
        u16* d = lds + b * 32768 + 16384 + h * 8192;
        async_load16(s + boff0, d + ldsw0);
        async_load16(s + boff1, d + ldsw1);
    };
    auto loadA = [&](int b, int h) {
        const u16* p = lds + b * 32768 + h * 8192 + aoffL;
        #pragma unroll
        for (int li = 0; li < 4; ++li) {
            a[li][0] = *(const bf16x8*)(p + li * 2048 + slot0);
            a[li][1] = *(const bf16x8*)(p + li * 2048 + slot1);
        }
    };
    auto loadB = [&](int b, int h) {
        const u16* p = lds + b * 32768 + h * 8192 + boffL;
        #pragma unroll
        for (int lj = 0; lj < 2; ++lj) {
            b2[lj][0] = *(const bf16x8*)(p + lj * 4096 + slot0);
            b2[lj][1] = *(const bf16x8*)(p + lj * 4096 + slot1);
        }
    };
    auto mfmaQ = [&](int mh, int nh) {
        #pragma unroll
        for (int li = 0; li < 4; ++li)
            #pragma unroll
            for (int lj = 0; lj < 2; ++lj) {
                f32x4 c = acc[mh * 4 + li][nh * 2 + lj];
                c = __builtin_amdgcn_mfma_f32_16x16x32_bf16(a[li][0], b2[lj][0], c, 0, 0, 0);
                c = __builtin_amdgcn_mfma_f32_16x16x32_bf16(a[li][1], b2[lj][1], c, 0, 0, 0);
                acc[mh * 4 + li][nh * 2 + lj] = c;
            }
    };

    // Prologue: tile0 (all 4 half-tiles) + tile1 A-h0,B-h0. 12 loads.
    stageA(0, 0, 0); stageB(0, 0, 0);
    stageA(0, 1, 0); stageB(0, 1, 0);
    stageA(1, 0, 1); stageB(1, 0, 1);
    asm volatile("s_waitcnt vmcnt(8)" ::: "memory");   // tile0 A-h0,B-h0 landed
    __builtin_amdgcn_s_barrier();

    for (int T = 0; T < NT; ++T) {
        const int bc = T & 1, bn = bc ^ 1;
        const int t1 = (T + 1) & (NT - 1);
        const int t2 = (T + 2) & (NT - 1);

        // phase 1: quadrant (0,0)
        loadA(bc, 0); loadB(bc, 0);
        stageA(bn, 1, t1);
        __builtin_amdgcn_s_barrier();
        asm volatile("s_waitcnt lgkmcnt(0)" ::: "memory");
        __builtin_amdgcn_s_setprio(1);
        mfmaQ(0, 0);
        __builtin_amdgcn_s_setprio(0);
        asm volatile("s_waitcnt vmcnt(6)" ::: "memory");  // (T)B-h1,(T)A-h1 landed
        __builtin_amdgcn_s_barrier();

        // phase 2: quadrant (0,1) — A regs kept
        loadB(bc, 1);
        stageB(bn, 1, t1);
        __builtin_amdgcn_s_barrier();
        asm volatile("s_waitcnt lgkmcnt(0)" ::: "memory");
        __builtin_amdgcn_s_setprio(1);
        mfmaQ(0, 1);
        __builtin_amdgcn_s_setprio(0);
        __builtin_amdgcn_s_barrier();

        // phase 3: quadrant (1,0)
        loadA(bc, 1); loadB(bc, 0);
        stageA(bc, 0, t2);
        __builtin_amdgcn_s_barrier();
        asm volatile("s_waitcnt lgkmcnt(0)" ::: "memory");
        __builtin_amdgcn_s_setprio(1);
        mfmaQ(1, 0);
        __builtin_amdgcn_s_setprio(0);
        __builtin_amdgcn_s_barrier();

        // phase 4: quadrant (1,1) — A regs kept
        loadB(bc, 1);
        stageB(bc, 0, t2);
        __builtin_amdgcn_s_barrier();
        asm volatile("s_waitcnt lgkmcnt(0)" ::: "memory");
        __builtin_amdgcn_s_setprio(1);
        mfmaQ(1, 1);
        __builtin_amdgcn_s_setprio(0);
        asm volatile("s_waitcnt vmcnt(8)" ::: "memory");  // (T+1)A-h0,B-h0 landed
        __builtin_amdgcn_s_barrier();
    }
    asm volatile("s_waitcnt vmcnt(0)" ::: "memory");  // drain tail dummy loads

    // Epilogue: C/D layout col = lane&15, row = (lane>>4)*4 + reg.
    #pragma unroll
    for (int j = 0; j < 4; ++j) {
        const int n = n0 + (j * 4 + wni) * 16 + lr;
        const float bv = bias[n];
        #pragma unroll
        for (int i = 0; i < 8; ++i) {
            const int mb = m0 + (2 * i + wmi) * 16 + lq * 4;
            #pragma unroll
            for (int r = 0; r < 4; ++r)
                out[(size_t)(mb + r) * N + n] = acc[i][j][r] + bv;
        }
    }
}

// ---------------------------------------------------------------------------
// Fallback (small workspace): 128^2 m97-structure GEMM reading f32 X directly.
// ---------------------------------------------------------------------------
#define TM 128
#define TN 128
#define BK 32

__global__ void gemm_bt_f32(const float* __restrict__ Xf, const u16* __restrict__ Gt,
                            const float* __restrict__ bias, float* __restrict__ out) {
    constexpr int K = 4096, N = 4096;
    __shared__ __attribute__((aligned(16))) u16 As[TM * BK];
    __shared__ __attribute__((aligned(16))) u16 Bs[TN * BK];

    const int tid  = threadIdx.x;
    const int lane = tid & 63;
    const int w    = tid >> 6;
    const int m0   = blockIdx.y * TM;
    const int n0   = blockIdx.x * TN;
    const int wm   = (w >> 1) * 64;
    const int wn   = (w & 1) * 64;
    const int lr   = lane & 15;
    const int lk   = (lane >> 4) * 8;

    f32x4 acc[4][4] = {};

    const int srow   = tid >> 2;
    const int schunk = (tid & 3) * 8;
    const u16* grow0 = Gt + (size_t)(n0 + srow) * K + schunk;
    const u16* grow1 = Gt + (size_t)(n0 + 64 + srow) * K + schunk;
    u16* ldsB0 = &Bs[(tid & ~63) * 8];
    u16* ldsB1 = &Bs[(256 + (tid & ~63)) * 8];

    const float* xsrc = Xf + (size_t)(m0 + (tid >> 1)) * K + (tid & 1) * 16;
    u16* adst = &As[(tid >> 1) * BK + (tid & 1) * 16];

    for (int k0 = 0; k0 < K; k0 += BK) {
        __syncthreads();
        {
            f32x4 v0 = ((const f32x4*)(xsrc + k0))[0];
            f32x4 v1 = ((const f32x4*)(xsrc + k0))[1];
            f32x4 v2 = ((const f32x4*)(xsrc + k0))[2];
            f32x4 v3 = ((const f32x4*)(xsrc + k0))[3];
            bf16x8 w0, w1;
            #pragma unroll
            for (int j = 0; j < 4; ++j) {
                w0[j]     = (short)f2bf(v0[j]);
                w0[4 + j] = (short)f2bf(v1[j]);
                w1[j]     = (short)f2bf(v2[j]);
                w1[4 + j] = (short)f2bf(v3[j]);
            }
            *(bf16x8*)adst = w0;
            *(bf16x8*)(adst + 8) = w1;
        }
        async_load16(grow0 + k0, ldsB0);
        async_load16(grow1 + k0, ldsB1);
        __syncthreads();

        bf16x8 af[4], bg[4];
        #pragma unroll
        for (int i = 0; i < 4; ++i) {
            af[i] = *(const bf16x8*)(&As[(wm + i * 16 + lr) * BK + lk]);
            bg[i] = *(const bf16x8*)(&Bs[(wn + i * 16 + lr) * BK + lk]);
        }
        #pragma unroll
        for (int mt = 0; mt < 4; ++mt)
            #pragma unroll
            for (int nt = 0; nt < 4; ++nt)
                acc[mt][nt] = __builtin_amdgcn_mfma_f32_16x16x32_bf16(
                    af[mt], bg[nt], acc[mt][nt], 0, 0, 0);
    }

    #pragma unroll
    for (int nt = 0; nt < 4; ++nt) {
        const int n = n0 + wn + nt * 16 + lr;
        const float bv = bias[n];
        #pragma unroll
        for (int mt = 0; mt < 4; ++mt) {
            const int mbase = m0 + wm + mt * 16 + (lane >> 4) * 4;
            #pragma unroll
            for (int r = 0; r < 4; ++r) {
                out[(size_t)(mbase + r) * N + n] = acc[mt][nt][r] + bv;
            }
        }
    }
}

extern "C" void kernel_launch(void* const* d_in, const int* in_sizes, int n_in,
                              void* d_out, int out_size, void* d_ws, size_t ws_size,
                              hipStream_t stream) {
    const float* x    = (const float*)d_in[0];  // (8,1024,4096) f32
    const float* c0   = (const float*)d_in[1];
    const float* c1   = (const float*)d_in[2];
    const float* c2   = (const float*)d_in[3];
    const float* bias = (const float*)d_in[4];
    float* out = (float*)d_out;

    const size_t GT_BYTES = (size_t)4096 * 4096 * sizeof(u16);   // 32 MB
    const size_t XB_BYTES = (size_t)8192 * 4096 * sizeof(u16);   // 64 MB
    u16* Gt = (u16*)d_ws;

    build_gt<<<dim3(256, 16), 256, 0, stream>>>(c0, c1, c2, Gt);

    if (ws_size >= GT_BYTES + XB_BYTES) {
        u16* Xb = (u16*)((char*)d_ws + GT_BYTES);
        conv_x<<<8192, 256, 0, stream>>>((const f32x4*)x, Xb, 8192 * 4096 / 4);
        static int attr_done = 0;
        if (!attr_done) {
            hipFuncSetAttribute(reinterpret_cast<const void*>(gemm_8ph),
                                hipFuncAttributeMaxDynamicSharedMemorySize, 131072);
            attr_done = 1;
        }
        gemm_8ph<<<dim3(16, 32), 512, 131072, stream>>>(Xb, Gt, bias, out);
    } else {
        gemm_bt_f32<<<dim3(32, 64), 256, 0, stream>>>(x, Gt, bias, out);
    }
}

// Round 2
// 501.484 us; speedup vs baseline: 1.1277x; 1.1277x over previous
//
#include <hip/hip_runtime.h>
#include <stdint.h>

typedef unsigned short u16;
typedef short bf16x8 __attribute__((ext_vector_type(8)));
typedef float f32x4 __attribute__((ext_vector_type(4)));
typedef u16 u16x4 __attribute__((ext_vector_type(4)));

__device__ __forceinline__ u16 f2bf(float f) {
    union { float f; unsigned int i; } v; v.f = f;
    unsigned int x = v.i;
    return (u16)((x + 0x7FFFu + ((x >> 16) & 1u)) >> 16);  // RNE
}

// Async global->LDS, 16B per lane. LDS dest is wave-uniform base; HW adds lane*16.
__device__ __forceinline__ void async_load16(const u16* g, u16* lds) {
    __builtin_amdgcn_global_load_lds(
        (const __attribute__((address_space(1))) unsigned int*)g,
        (__attribute__((address_space(3))) unsigned int*)lds,
        16, 0, 0);
}

// ---------------------------------------------------------------------------
// Plain transpose [4096][Q] f32 -> [Q][4096].  All three core access patterns
// reduce to this: c0:(r*16+y1)*8+b = r*128+q; c1: r*1024+q; c2: r*128+q.
// Tiled 64x64 via LDS, both sides coalesced.
// ---------------------------------------------------------------------------
__global__ void transpose_f32(const float* __restrict__ in, float* __restrict__ out,
                              int Q) {
    __shared__ float t[64][65];
    const int r0 = blockIdx.y * 64;
    const int q0 = blockIdx.x * 64;
    const int tx = threadIdx.x & 63;
    const int ty = threadIdx.x >> 6;   // 0..3
    #pragma unroll
    for (int k = 0; k < 16; ++k) {
        const int row = k * 4 + ty;
        t[row][tx] = in[(size_t)(r0 + row) * Q + q0 + tx];
    }
    __syncthreads();
    #pragma unroll
    for (int k = 0; k < 16; ++k) {
        const int qrow = k * 4 + ty;
        out[(size_t)(q0 + qrow) * 4096 + r0 + tx] = t[tx][qrow];
    }
}

// ---------------------------------------------------------------------------
// build_gt from TRANSPOSED cores: every load is lane-coalesced f32x4 (r inner).
// Thread handles 4 consecutive r for one (y1,x1); 16 x2 outputs each.
//   Gt[col][r], col = y1*256 + x1*16 + x2.
// grid (256,4) x 256 thr: bx=(y1,x1), p=r-chunk; r0 = p*1024 + tid*4.
// ---------------------------------------------------------------------------
__global__ void build_gt_t(const float* __restrict__ c0t, const float* __restrict__ c1t,
                           const float* __restrict__ c2t, u16* __restrict__ Gt) {
    const int y1 = blockIdx.x >> 4;
    const int x1 = blockIdx.x & 15;
    const int r0 = blockIdx.y * 1024 + threadIdx.x * 4;

    f32x4 a0[8];
    #pragma unroll
    for (int b = 0; b < 8; ++b)
        a0[b] = *(const f32x4*)(c0t + (size_t)(y1 * 8 + b) * 4096 + r0);

    f32x4 t[8];
    #pragma unroll
    for (int c = 0; c < 8; ++c) {
        f32x4 s = {0.f, 0.f, 0.f, 0.f};
        #pragma unroll
        for (int b = 0; b < 8; ++b) {
            f32x4 w = *(const f32x4*)(c1t + (size_t)(x1 * 64 + c * 8 + b) * 4096 + r0);
            s += w * a0[b];
        }
        t[c] = s;
    }
    #pragma unroll
    for (int x2 = 0; x2 < 16; ++x2) {
        f32x4 s = {0.f, 0.f, 0.f, 0.f};
        #pragma unroll
        for (int c = 0; c < 8; ++c) {
            f32x4 w = *(const f32x4*)(c2t + (size_t)(x2 * 8 + c) * 4096 + r0);
            s += w * t[c];
        }
        u16x4 o;
        #pragma unroll
        for (int j = 0; j < 4; ++j) o[j] = f2bf(s[j]);
        *(u16x4*)(Gt + (size_t)(blockIdx.x * 16 + x2) * 4096 + r0) = o;
    }
}

// ---------------------------------------------------------------------------
// Fallback build_gt (unchanged, verified): scalar reads from original cores.
// ---------------------------------------------------------------------------
__global__ void build_gt(const float* __restrict__ c0, const float* __restrict__ c1,
                         const float* __restrict__ c2, u16* __restrict__ Gt) {
    const int y1  = blockIdx.x >> 4;
    const int x1  = blockIdx.x & 15;
    const int r   = blockIdx.y * 256 + threadIdx.x;

    float a0[8];
    {
        f32x4 v0 = *(const f32x4*)(c0 + ((size_t)r * 16 + y1) * 8);
        f32x4 v1 = *(const f32x4*)(c0 + ((size_t)r * 16 + y1) * 8 + 4);
        #pragma unroll
        for (int b = 0; b < 4; ++b) { a0[b] = v0[b]; a0[4 + b] = v1[b]; }
    }
    float t[8];
    const float* c1row = c1 + ((size_t)r * 16 + x1) * 64;
    #pragma unroll
    for (int c = 0; c < 8; ++c) {
        f32x4 v0 = *(const f32x4*)(c1row + c * 8);
        f32x4 v1 = *(const f32x4*)(c1row + c * 8 + 4);
        float s = 0.f;
        #pragma unroll
        for (int b = 0; b < 4; ++b) s += v0[b] * a0[b] + v1[b] * a0[4 + b];
        t[c] = s;
    }
    const float* c2row = c2 + (size_t)r * 128;
    #pragma unroll
    for (int x2 = 0; x2 < 16; ++x2) {
        f32x4 v0 = *(const f32x4*)(c2row + x2 * 8);
        f32x4 v1 = *(const f32x4*)(c2row + x2 * 8 + 4);
        float s = 0.f;
        #pragma unroll
        for (int c = 0; c < 4; ++c) s += v0[c] * t[c] + v1[c] * t[4 + c];
        Gt[((size_t)(blockIdx.x * 16 + x2)) * 4096 + r] = f2bf(s);
    }
}

// X: f32 -> bf16, vectorized. (unchanged, verified)
__global__ void conv_x(const f32x4* __restrict__ x, u16* __restrict__ xb, int n4) {
    for (int i = blockIdx.x * 256 + threadIdx.x; i < n4; i += gridDim.x * 256) {
        f32x4 v = x[i];
        u16x4 o;
        #pragma unroll
        for (int j = 0; j < 4; ++j) o[j] = f2bf(v[j]);
        *(u16x4*)(xb + 4 * (size_t)i) = o;
    }
}

// ---------------------------------------------------------------------------
// 256x256 8-phase GEMM (T2+T3+T4+T5), C = X(bf16) @ Gt^T + bias.
// v2: B-halves held in registers across the whole K-tile -> LDS reads per
// wave per tile drop 32 -> 24 b128 (A 16KB + B 8KB, no B re-read). LDS BW
// was the critical path (3080 cyc/tile vs MFMA 2483); now MFMA-bound.
// Per-phase ds_reads: 12 / 4 / 8 / 0.  vmcnt guards UNCHANGED (FIFO:
// end-ph4 vmcnt(8) drains A0,B0(T+1); end-ph1 vmcnt(6) drains A1,B1(T)).
// ---------------------------------------------------------------------------
__global__ __launch_bounds__(512, 2)
void gemm_8ph(const u16* __restrict__ Xb, const u16* __restrict__ Gt,
              const float* __restrict__ bias, float* __restrict__ out) {
    constexpr int K = 4096, N = 4096, NT = 64;
    extern __shared__ u16 lds[];  // 65536 u16 = 128 KiB

    const int tid  = threadIdx.x;
    const int lane = tid & 63;
    const int w    = tid >> 6;
    const int wmi  = w >> 2;       // 0..1
    const int wni  = w & 3;        // 0..3
    const int lr   = lane & 15;
    const int lq   = lane >> 4;    // 0..3
    const int xr   = lr & 7;       // xor bits for swizzle

    const int m0 = blockIdx.y * 256;
    const int n0 = blockIdx.x * 256;

    // --- staging maps (2 issues per thread per half-tile of 128x64 bf16) ---
    const int r0 = tid >> 3;                 // 0..63
    const int s0 = (tid & 7) ^ (r0 & 7);     // inverse-swizzled slot
    const int r1 = 64 + r0;                  // issue 1
    const int s1 = ((512 + tid) & 7) ^ (r1 & 7);
    const size_t aoff0 = (size_t)(m0 + r0) * K + s0 * 8;
    const size_t aoff1 = (size_t)(m0 + r1) * K + s1 * 8;
    const size_t boff0 = (size_t)(n0 + r0) * K + s0 * 8;
    const size_t boff1 = (size_t)(n0 + r1) * K + s1 * 8;
    const int ldsw0 = (tid & ~63) * 8;           // wave-uniform LDS base, issue 0
    const int ldsw1 = 4096 + (tid & ~63) * 8;    // issue 1

    // --- ds_read bases (u16 units). Region: A at 0, B at 16384; half*8192. ---
    const int aoffL = (wmi * 16 + lr) * 64;
    const int boffL = 16384 + (wni * 16 + lr) * 64;
    const int slot0 = (lq ^ xr) * 8;            // kk=0 swizzled 16B slot
    const int slot1 = ((4 + lq) ^ xr) * 8;      // kk=1

    f32x4 acc[8][4] = {};
    bf16x8 a[4][2];          // A-half frags (reloaded ph1/ph3)
    bf16x8 bfr[2][2][2];     // [half][lj][kk] — held across the whole tile

    auto stageA = [&](int bb, int h, int t) {
        const u16* s = Xb + (size_t)h * (128 * K) + (size_t)t * 64;
        u16* d = lds + bb * 32768 + h * 8192;
        async_load16(s + aoff0, d + ldsw0);
        async_load16(s + aoff1, d + ldsw1);
    };
    auto stageB = [&](int bb, int h, int t) {
        const u16* s = Gt + (size_t)h * (128 * K) + (size_t)t * 64;
        u16* d = lds + bb * 32768 + 16384 + h * 8192;
        async_load16(s + boff0, d + ldsw0);
        async_load16(s + boff1, d + ldsw1);
    };
    auto loadA = [&](int bb, int h) {
        const u16* p = lds + bb * 32768 + h * 8192 + aoffL;
        #pragma unroll
        for (int li = 0; li < 4; ++li) {
            a[li][0] = *(const bf16x8*)(p + li * 2048 + slot0);
            a[li][1] = *(const bf16x8*)(p + li * 2048 + slot1);
        }
    };
    auto loadB = [&](int bb, int h) {
        const u16* p = lds + bb * 32768 + h * 8192 + boffL;
        #pragma unroll
        for (int lj = 0; lj < 2; ++lj) {
            bfr[h][lj][0] = *(const bf16x8*)(p + lj * 4096 + slot0);
            bfr[h][lj][1] = *(const bf16x8*)(p + lj * 4096 + slot1);
        }
    };
    auto mfmaQ = [&](int mh, int nh) {
        #pragma unroll
        for (int li = 0; li < 4; ++li)
            #pragma unroll
            for (int lj = 0; lj < 2; ++lj) {
                f32x4 c = acc[mh * 4 + li][nh * 2 + lj];
                c = __builtin_amdgcn_mfma_f32_16x16x32_bf16(a[li][0], bfr[nh][lj][0], c, 0, 0, 0);
                c = __builtin_amdgcn_mfma_f32_16x16x32_bf16(a[li][1], bfr[nh][lj][1], c, 0, 0, 0);
                acc[mh * 4 + li][nh * 2 + lj] = c;
            }
    };

    // Prologue: tile0 (all 4 half-tiles) + tile1 A-h0,B-h0. 12 loads.
    stageA(0, 0, 0); stageB(0, 0, 0);
    stageA(0, 1, 0); stageB(0, 1, 0);
    stageA(1, 0, 1); stageB(1, 0, 1);
    asm volatile("s_waitcnt vmcnt(8)" ::: "memory");   // tile0 A-h0,B-h0 landed
    __builtin_amdgcn_s_barrier();

    for (int T = 0; T < NT; ++T) {
        const int bc = T & 1, bn = bc ^ 1;
        const int t1 = (T + 1) & (NT - 1);
        const int t2 = (T + 2) & (NT - 1);

        // phase 1: quadrant (0,0) — read A0 + B0 (held all tile)
        loadA(bc, 0); loadB(bc, 0);
        stageA(bn, 1, t1);
        __builtin_amdgcn_s_barrier();
        asm volatile("s_waitcnt lgkmcnt(0)" ::: "memory");
        __builtin_amdgcn_s_setprio(1);
        mfmaQ(0, 0);
        __builtin_amdgcn_s_setprio(0);
        asm volatile("s_waitcnt vmcnt(6)" ::: "memory");  // (T)A-h1,(T)B-h1 landed
        __builtin_amdgcn_s_barrier();

        // phase 2: quadrant (0,1) — read B1 (held), A regs kept
        loadB(bc, 1);
        stageB(bn, 1, t1);
        __builtin_amdgcn_s_barrier();
        asm volatile("s_waitcnt lgkmcnt(0)" ::: "memory");
        __builtin_amdgcn_s_setprio(1);
        mfmaQ(0, 1);
        __builtin_amdgcn_s_setprio(0);
        __builtin_amdgcn_s_barrier();

        // phase 3: quadrant (1,0) — read A1 only; B0 still in regs
        loadA(bc, 1);
        stageA(bc, 0, t2);
        __builtin_amdgcn_s_barrier();
        asm volatile("s_waitcnt lgkmcnt(0)" ::: "memory");
        __builtin_amdgcn_s_setprio(1);
        mfmaQ(1, 0);
        __builtin_amdgcn_s_setprio(0);
        __builtin_amdgcn_s_barrier();

        // phase 4: quadrant (1,1) — no ds_reads; B1 in regs
        stageB(bc, 0, t2);
        __builtin_amdgcn_s_barrier();
        __builtin_amdgcn_s_setprio(1);
        mfmaQ(1, 1);
        __builtin_amdgcn_s_setprio(0);
        asm volatile("s_waitcnt vmcnt(8)" ::: "memory");  // (T+1)A-h0,B-h0 landed
        __builtin_amdgcn_s_barrier();
    }
    asm volatile("s_waitcnt vmcnt(0)" ::: "memory");  // drain tail dummy loads

    // Epilogue: C/D layout col = lane&15, row = (lane>>4)*4 + reg.
    #pragma unroll
    for (int j = 0; j < 4; ++j) {
        const int n = n0 + (j * 4 + wni) * 16 + lr;
        const float bv = bias[n];
        #pragma unroll
        for (int i = 0; i < 8; ++i) {
            const int mb = m0 + (2 * i + wmi) * 16 + lq * 4;
            #pragma unroll
            for (int r = 0; r < 4; ++r)
                out[(size_t)(mb + r) * N + n] = acc[i][j][r] + bv;
        }
    }
}

// ---------------------------------------------------------------------------
// Fallback (small workspace): 128^2 m97-structure GEMM reading f32 X directly.
// ---------------------------------------------------------------------------
#define TM 128
#define TN 128
#define BK 32

__global__ void gemm_bt_f32(const float* __restrict__ Xf, const u16* __restrict__ Gt,
                            const float* __restrict__ bias, float* __restrict__ out) {
    constexpr int K = 4096, N = 4096;
    __shared__ __attribute__((aligned(16))) u16 As[TM * BK];
    __shared__ __attribute__((aligned(16))) u16 Bs[TN * BK];

    const int tid  = threadIdx.x;
    const int lane = tid & 63;
    const int w    = tid >> 6;
    const int m0   = blockIdx.y * TM;
    const int n0   = blockIdx.x * TN;
    const int wm   = (w >> 1) * 64;
    const int wn   = (w & 1) * 64;
    const int lr   = lane & 15;
    const int lk   = (lane >> 4) * 8;

    f32x4 acc[4][4] = {};

    const int srow   = tid >> 2;
    const int schunk = (tid & 3) * 8;
    const u16* grow0 = Gt + (size_t)(n0 + srow) * K + schunk;
    const u16* grow1 = Gt + (size_t)(n0 + 64 + srow) * K + schunk;
    u16* ldsB0 = &Bs[(tid & ~63) * 8];
    u16* ldsB1 = &Bs[(256 + (tid & ~63)) * 8];

    const float* xsrc = Xf + (size_t)(m0 + (tid >> 1)) * K + (tid & 1) * 16;
    u16* adst = &As[(tid >> 1) * BK + (tid & 1) * 16];

    for (int k0 = 0; k0 < K; k0 += BK) {
        __syncthreads();
        {
            f32x4 v0 = ((const f32x4*)(xsrc + k0))[0];
            f32x4 v1 = ((const f32x4*)(xsrc + k0))[1];
            f32x4 v2 = ((const f32x4*)(xsrc + k0))[2];
            f32x4 v3 = ((const f32x4*)(xsrc + k0))[3];
            bf16x8 w0, w1;
            #pragma unroll
            for (int j = 0; j < 4; ++j) {
                w0[j]     = (short)f2bf(v0[j]);
                w0[4 + j] = (short)f2bf(v1[j]);
                w1[j]     = (short)f2bf(v2[j]);
                w1[4 + j] = (short)f2bf(v3[j]);
            }
            *(bf16x8*)adst = w0;
            *(bf16x8*)(adst + 8) = w1;
        }
        async_load16(grow0 + k0, ldsB0);
        async_load16(grow1 + k0, ldsB1);
        __syncthreads();

        bf16x8 af[4], bg[4];
        #pragma unroll
        for (int i = 0; i < 4; ++i) {
            af[i] = *(const bf16x8*)(&As[(wm + i * 16 + lr) * BK + lk]);
            bg[i] = *(const bf16x8*)(&Bs[(wn + i * 16 + lr) * BK + lk]);
        }
        #pragma unroll
        for (int mt = 0; mt < 4; ++mt)
            #pragma unroll
            for (int nt = 0; nt < 4; ++nt)
                acc[mt][nt] = __builtin_amdgcn_mfma_f32_16x16x32_bf16(
                    af[mt], bg[nt], acc[mt][nt], 0, 0, 0);
    }

    #pragma unroll
    for (int nt = 0; nt < 4; ++nt) {
        const int n = n0 + wn + nt * 16 + lr;
        const float bv = bias[n];
        #pragma unroll
        for (int mt = 0; mt < 4; ++mt) {
            const int mbase = m0 + wm + mt * 16 + (lane >> 4) * 4;
            #pragma unroll
            for (int r = 0; r < 4; ++r) {
                out[(size_t)(mbase + r) * N + n] = acc[mt][nt][r] + bv;
            }
        }
    }
}

extern "C" void kernel_launch(void* const* d_in, const int* in_sizes, int n_in,
                              void* d_out, int out_size, void* d_ws, size_t ws_size,
                              hipStream_t stream) {
    const float* x    = (const float*)d_in[0];  // (8,1024,4096) f32
    const float* c0   = (const float*)d_in[1];  // [4096][128] f32 (flattened)
    const float* c1   = (const float*)d_in[2];  // [4096][1024] f32
    const float* c2   = (const float*)d_in[3];  // [4096][128] f32
    const float* bias = (const float*)d_in[4];
    float* out = (float*)d_out;

    const size_t GT_BYTES = (size_t)4096 * 4096 * sizeof(u16);   // 32 MB
    const size_t XB_BYTES = (size_t)8192 * 4096 * sizeof(u16);   // 64 MB
    u16* Gt = (u16*)d_ws;

    if (ws_size >= GT_BYTES + XB_BYTES) {
        // Stage transposed cores in the Xb region (overwritten later by conv_x;
        // same-stream serialization makes this safe): c1t 16MB, c0t 2MB, c2t 2MB.
        char* scratch = (char*)d_ws + GT_BYTES;
        float* c1t = (float*)scratch;
        float* c0t = (float*)(scratch + (size_t)16 * 1024 * 1024);
        float* c2t = (float*)(scratch + (size_t)18 * 1024 * 1024);

        transpose_f32<<<dim3(16, 64), 256, 0, stream>>>(c1, c1t, 1024);
        transpose_f32<<<dim3(2, 64), 256, 0, stream>>>(c0, c0t, 128);
        transpose_f32<<<dim3(2, 64), 256, 0, stream>>>(c2, c2t, 128);
        build_gt_t<<<dim3(256, 4), 256, 0, stream>>>(c0t, c1t, c2t, Gt);

        u16* Xb = (u16*)((char*)d_ws + GT_BYTES);
        conv_x<<<8192, 256, 0, stream>>>((const f32x4*)x, Xb, 8192 * 4096 / 4);

        static int attr_done = 0;
        if (!attr_done) {
            hipFuncSetAttribute(reinterpret_cast<const void*>(gemm_8ph),
                                hipFuncAttributeMaxDynamicSharedMemorySize, 131072);
            attr_done = 1;
        }
        gemm_8ph<<<dim3(16, 32), 512, 131072, stream>>>(Xb, Gt, bias, out);
    } else {
        build_gt<<<dim3(256, 16), 256, 0, stream>>>(c0, c1, c2, Gt);
        gemm_bt_f32<<<dim3(32, 64), 256, 0, stream>>>(x, Gt, bias, out);
    }
}

// Round 3
// 498.711 us; speedup vs baseline: 1.1340x; 1.0056x over previous
//
#include <hip/hip_runtime.h>
#include <stdint.h>

typedef unsigned short u16;
typedef short bf16x8 __attribute__((ext_vector_type(8)));
typedef float f32x4 __attribute__((ext_vector_type(4)));
typedef u16 u16x4 __attribute__((ext_vector_type(4)));

__device__ __forceinline__ u16 f2bf(float f) {
    union { float f; unsigned int i; } v; v.f = f;
    unsigned int x = v.i;
    return (u16)((x + 0x7FFFu + ((x >> 16) & 1u)) >> 16);  // RNE
}

// Async global->LDS, 16B per lane. LDS dest is wave-uniform base; HW adds lane*16.
__device__ __forceinline__ void async_load16(const u16* g, u16* lds) {
    __builtin_amdgcn_global_load_lds(
        (const __attribute__((address_space(1))) unsigned int*)g,
        (__attribute__((address_space(3))) unsigned int*)lds,
        16, 0, 0);
}

// ---------------------------------------------------------------------------
// Plain transpose [4096][Q] f32 -> [Q][4096]. Tiled 64x64 via LDS.
// ---------------------------------------------------------------------------
__global__ void transpose_f32(const float* __restrict__ in, float* __restrict__ out,
                              int Q) {
    __shared__ float t[64][65];
    const int r0 = blockIdx.y * 64;
    const int q0 = blockIdx.x * 64;
    const int tx = threadIdx.x & 63;
    const int ty = threadIdx.x >> 6;   // 0..3
    #pragma unroll
    for (int k = 0; k < 16; ++k) {
        const int row = k * 4 + ty;
        t[row][tx] = in[(size_t)(r0 + row) * Q + q0 + tx];
    }
    __syncthreads();
    #pragma unroll
    for (int k = 0; k < 16; ++k) {
        const int qrow = k * 4 + ty;
        out[(size_t)(q0 + qrow) * 4096 + r0 + tx] = t[tx][qrow];
    }
}

// ---------------------------------------------------------------------------
// build_gt from TRANSPOSED cores, XCD-chunked swizzle so each XCD's L2 holds
// its 2 c1t slices (2MB) + c2t (2MB): the ~800MB of c1t/c2t re-reads become
// L2 hits. 1D grid 1024 blocks; id layout x1-major after swizzle.
// ---------------------------------------------------------------------------
__global__ void build_gt_t(const float* __restrict__ c0t, const float* __restrict__ c1t,
                           const float* __restrict__ c2t, u16* __restrict__ Gt) {
    int id = blockIdx.x;                   // 0..1023, 1024 % 8 == 0
    id = (id & 7) * 128 + (id >> 3);       // XCD gets contiguous 128 ids
    const int x1 = id >> 6;                // 0..15 (2 per XCD)
    const int y1 = (id >> 2) & 15;
    const int p  = id & 3;
    const int r0 = p * 1024 + threadIdx.x * 4;
    const int colb = (y1 * 16 + x1) * 16;

    f32x4 a0[8];
    #pragma unroll
    for (int b = 0; b < 8; ++b)
        a0[b] = *(const f32x4*)(c0t + (size_t)(y1 * 8 + b) * 4096 + r0);

    f32x4 t[8];
    #pragma unroll
    for (int c = 0; c < 8; ++c) {
        f32x4 s = {0.f, 0.f, 0.f, 0.f};
        #pragma unroll
        for (int b = 0; b < 8; ++b) {
            f32x4 w = *(const f32x4*)(c1t + (size_t)(x1 * 64 + c * 8 + b) * 4096 + r0);
            s += w * a0[b];
        }
        t[c] = s;
    }
    #pragma unroll
    for (int x2 = 0; x2 < 16; ++x2) {
        f32x4 s = {0.f, 0.f, 0.f, 0.f};
        #pragma unroll
        for (int c = 0; c < 8; ++c) {
            f32x4 w = *(const f32x4*)(c2t + (size_t)(x2 * 8 + c) * 4096 + r0);
            s += w * t[c];
        }
        u16x4 o;
        #pragma unroll
        for (int j = 0; j < 4; ++j) o[j] = f2bf(s[j]);
        *(u16x4*)(Gt + (size_t)(colb + x2) * 4096 + r0) = o;
    }
}

// ---------------------------------------------------------------------------
// Fallback build_gt (verified): scalar reads from original cores.
// ---------------------------------------------------------------------------
__global__ void build_gt(const float* __restrict__ c0, const float* __restrict__ c1,
                         const float* __restrict__ c2, u16* __restrict__ Gt) {
    const int y1  = blockIdx.x >> 4;
    const int x1  = blockIdx.x & 15;
    const int r   = blockIdx.y * 256 + threadIdx.x;

    float a0[8];
    {
        f32x4 v0 = *(const f32x4*)(c0 + ((size_t)r * 16 + y1) * 8);
        f32x4 v1 = *(const f32x4*)(c0 + ((size_t)r * 16 + y1) * 8 + 4);
        #pragma unroll
        for (int b = 0; b < 4; ++b) { a0[b] = v0[b]; a0[4 + b] = v1[b]; }
    }
    float t[8];
    const float* c1row = c1 + ((size_t)r * 16 + x1) * 64;
    #pragma unroll
    for (int c = 0; c < 8; ++c) {
        f32x4 v0 = *(const f32x4*)(c1row + c * 8);
        f32x4 v1 = *(const f32x4*)(c1row + c * 8 + 4);
        float s = 0.f;
        #pragma unroll
        for (int b = 0; b < 4; ++b) s += v0[b] * a0[b] + v1[b] * a0[4 + b];
        t[c] = s;
    }
    const float* c2row = c2 + (size_t)r * 128;
    #pragma unroll
    for (int x2 = 0; x2 < 16; ++x2) {
        f32x4 v0 = *(const f32x4*)(c2row + x2 * 8);
        f32x4 v1 = *(const f32x4*)(c2row + x2 * 8 + 4);
        float s = 0.f;
        #pragma unroll
        for (int c = 0; c < 4; ++c) s += v0[c] * t[c] + v1[c] * t[4 + c];
        Gt[((size_t)(blockIdx.x * 16 + x2)) * 4096 + r] = f2bf(s);
    }
}

// X: f32 -> bf16, vectorized. (unchanged, verified)
__global__ void conv_x(const f32x4* __restrict__ x, u16* __restrict__ xb, int n4) {
    for (int i = blockIdx.x * 256 + threadIdx.x; i < n4; i += gridDim.x * 256) {
        f32x4 v = x[i];
        u16x4 o;
        #pragma unroll
        for (int j = 0; j < 4; ++j) o[j] = f2bf(v[j]);
        *(u16x4*)(xb + 4 * (size_t)i) = o;
    }
}

// ---------------------------------------------------------------------------
// 256x256 GEMM v3: gray-code quadrants + all frag ds_reads overlapped under
// MFMA clusters. C = X(bf16) @ Gt^T + bias.  M=8192, N=K=4096.
//
// Gray order (0,0)->(0,1)->(1,1)->(1,0): A-halves in adjacent pairs, B-halves
// held in regs all tile. Frag reads placement (all drain under MFMA):
//   ph4(T-1): B1'(pre-Q4), A0' (interleaved per-li IN Q4), B0' (post-Q4)
//   ph2(T):   A1 refill interleaved per-li IN Q2 (WAR keeps order, 0 extra regs)
// Barriers 3/tile: ph1 (guards A0/B0/B1-frag reads vs ph2/ph4 staging of T+2),
// ph3 (guards A1 reads vs ph4 staging), ph4 publish (vmcnt(8), counts T+2's 8).
// Q1/Q3 touch no LDS; all spans between barriers touch disjoint regions.
// All lgkm waits are lgkmcnt(0) -> robust to issue reorder; only vmcnt counted.
// XCD swizzle: each XCD gets 2 n-panels (4MB Gt, L2-fit) x 32 m.
// ---------------------------------------------------------------------------
__global__ __launch_bounds__(512, 2)
void gemm_8ph(const u16* __restrict__ Xb, const u16* __restrict__ Gt,
              const float* __restrict__ bias, float* __restrict__ out) {
    constexpr int K = 4096, N = 4096, NT = 64;
    extern __shared__ u16 lds[];  // 128 KiB

    const int tid  = threadIdx.x;
    const int lane = tid & 63;
    const int w    = tid >> 6;
    const int wmi  = w >> 2;       // 0..1
    const int wni  = w & 3;        // 0..3
    const int lr   = lane & 15;
    const int lq   = lane >> 4;    // 0..3
    const int xr   = lr & 7;

    int id = blockIdx.y * 16 + blockIdx.x;   // 0..511, 512 % 8 == 0
    id = (id & 7) * 64 + (id >> 3);          // XCD-chunk swizzle
    const int m0 = (id & 31) * 256;
    const int n0 = (id >> 5) * 256;          // 2 n-panels per XCD -> L2-fit Gt

    // --- staging maps (2 issues per thread per half-tile of 128x64 bf16) ---
    const int r0 = tid >> 3;
    const int s0 = (tid & 7) ^ (r0 & 7);
    const int r1 = 64 + r0;
    const int s1 = ((512 + tid) & 7) ^ (r1 & 7);
    const size_t aoff0 = (size_t)(m0 + r0) * K + s0 * 8;
    const size_t aoff1 = (size_t)(m0 + r1) * K + s1 * 8;
    const size_t boff0 = (size_t)(n0 + r0) * K + s0 * 8;
    const size_t boff1 = (size_t)(n0 + r1) * K + s1 * 8;
    const int ldsw0 = (tid & ~63) * 8;
    const int ldsw1 = 4096 + (tid & ~63) * 8;

    // --- ds_read bases (u16 units). A at 0, B at 16384; half*8192. ---
    const int aoffL = (wmi * 16 + lr) * 64;
    const int boffL = 16384 + (wni * 16 + lr) * 64;
    const int slot0 = (lq ^ xr) * 8;
    const int slot1 = ((4 + lq) ^ xr) * 8;

    f32x4 acc[8][4] = {};
    bf16x8 a[4][2];          // current A-half frags (refilled in-place)
    bf16x8 bfr[2][2][2];     // [half][lj][kk] — whole tile

    auto stageA = [&](int bb, int h, int t) {
        const u16* s = Xb + (size_t)h * (128 * K) + (size_t)t * 64;
        u16* d = lds + bb * 32768 + h * 8192;
        async_load16(s + aoff0, d + ldsw0);
        async_load16(s + aoff1, d + ldsw1);
    };
    auto stageB = [&](int bb, int h, int t) {
        const u16* s = Gt + (size_t)h * (128 * K) + (size_t)t * 64;
        u16* d = lds + bb * 32768 + 16384 + h * 8192;
        async_load16(s + boff0, d + ldsw0);
        async_load16(s + boff1, d + ldsw1);
    };
    auto loadA = [&](int bb, int h) {
        const u16* p = lds + bb * 32768 + h * 8192 + aoffL;
        #pragma unroll
        for (int li = 0; li < 4; ++li) {
            a[li][0] = *(const bf16x8*)(p + li * 2048 + slot0);
            a[li][1] = *(const bf16x8*)(p + li * 2048 + slot1);
        }
    };
    auto loadB = [&](int bb, int h) {
        const u16* p = lds + bb * 32768 + h * 8192 + boffL;
        #pragma unroll
        for (int lj = 0; lj < 2; ++lj) {
            bfr[h][lj][0] = *(const bf16x8*)(p + lj * 4096 + slot0);
            bfr[h][lj][1] = *(const bf16x8*)(p + lj * 4096 + slot1);
        }
    };
    auto mfmaQ = [&](int mh, int nh) {
        #pragma unroll
        for (int li = 0; li < 4; ++li)
            #pragma unroll
            for (int lj = 0; lj < 2; ++lj) {
                f32x4 c = acc[mh * 4 + li][nh * 2 + lj];
                c = __builtin_amdgcn_mfma_f32_16x16x32_bf16(a[li][0], bfr[nh][lj][0], c, 0, 0, 0);
                c = __builtin_amdgcn_mfma_f32_16x16x32_bf16(a[li][1], bfr[nh][lj][1], c, 0, 0, 0);
                acc[mh * 4 + li][nh * 2 + lj] = c;
            }
    };
    // Quadrant MFMA with per-li A refill from pA: ds_read of a[li] is issued
    // right after the 4 MFMAs consuming a[li] (WAR dependency keeps order) so
    // the reads drain under the remaining MFMAs.
    auto mfmaQ_refillA = [&](int mh, int nh, const u16* pA) {
        #pragma unroll
        for (int li = 0; li < 4; ++li) {
            #pragma unroll
            for (int lj = 0; lj < 2; ++lj) {
                f32x4 c = acc[mh * 4 + li][nh * 2 + lj];
                c = __builtin_amdgcn_mfma_f32_16x16x32_bf16(a[li][0], bfr[nh][lj][0], c, 0, 0, 0);
                c = __builtin_amdgcn_mfma_f32_16x16x32_bf16(a[li][1], bfr[nh][lj][1], c, 0, 0, 0);
                acc[mh * 4 + li][nh * 2 + lj] = c;
            }
            a[li][0] = *(const bf16x8*)(pA + li * 2048 + slot0);
            a[li][1] = *(const bf16x8*)(pA + li * 2048 + slot1);
        }
    };

    // Prologue: tile0 (8 loads) + tile1 (8 loads); publish tile0; preload frags.
    stageA(0, 0, 0); stageB(0, 0, 0); stageA(0, 1, 0); stageB(0, 1, 0);
    stageA(1, 0, 1); stageB(1, 0, 1); stageA(1, 1, 1); stageB(1, 1, 1);
    asm volatile("s_waitcnt vmcnt(8)" ::: "memory");   // tile0 landed
    __builtin_amdgcn_s_barrier();
    loadB(0, 1); loadA(0, 0); loadB(0, 0);             // tile0 frags: B1, A0, B0

    for (int T = 0; T < NT; ++T) {
        const int bc = T & 1, bn = bc ^ 1;
        const int t2 = (T + 2) & (NT - 1);

        // ph1: Q1=(0,0) — pure regs. lgkm(0) covers B1',A0',B0' from ph4(T-1);
        // barrier legalizes ph2/ph4 staging over the A0/B0/B1 regions of bc.
        asm volatile("s_waitcnt lgkmcnt(0)" ::: "memory");
        __builtin_amdgcn_s_barrier();
        __builtin_amdgcn_sched_barrier(0);
        __builtin_amdgcn_s_setprio(1);
        mfmaQ(0, 0);
        __builtin_amdgcn_s_setprio(0);

        // ph2: stage T+2 h0 -> bc (regions A0,B0: reads done per ph1 barrier);
        // Q2=(0,1) with in-place A1 refill from bc (region disjoint from stage).
        stageA(bc, 0, t2); stageB(bc, 0, t2);
        __builtin_amdgcn_s_setprio(1);
        mfmaQ_refillA(0, 1, lds + bc * 32768 + 8192 + aoffL);
        __builtin_amdgcn_s_setprio(0);

        // ph3: Q3=(1,1) — pure regs. lgkm(0) covers A1 refill; barrier
        // legalizes ph4's staging over bc's A1/B1 regions.
        asm volatile("s_waitcnt lgkmcnt(0)" ::: "memory");
        __builtin_amdgcn_s_barrier();
        __builtin_amdgcn_sched_barrier(0);
        __builtin_amdgcn_s_setprio(1);
        mfmaQ(1, 1);
        __builtin_amdgcn_s_setprio(0);

        // ph4: stage T+2 h1 -> bc; publish bn (tile T+1): vmcnt(8) leaves
        // exactly T+2's 8 loads in flight. Then prefetch next-tile frags from
        // bn under Q4: B1' before (bfr[1] dead after Q3), A0' interleaved in
        // Q4 (a[] WAR), B0' after (bfr[0] live through Q4).
        stageA(bc, 1, t2); stageB(bc, 1, t2);
        asm volatile("s_waitcnt vmcnt(8)" ::: "memory");
        __builtin_amdgcn_s_barrier();
        __builtin_amdgcn_sched_barrier(0);
        loadB(bn, 1);
        __builtin_amdgcn_s_setprio(1);
        mfmaQ_refillA(1, 0, lds + bn * 32768 + aoffL);
        __builtin_amdgcn_s_setprio(0);
        loadB(bn, 0);
    }
    asm volatile("s_waitcnt vmcnt(0) lgkmcnt(0)" ::: "memory");  // drain tail

    // Epilogue: C/D layout col = lane&15, row = (lane>>4)*4 + reg.
    #pragma unroll
    for (int j = 0; j < 4; ++j) {
        const int n = n0 + (j * 4 + wni) * 16 + lr;
        const float bv = bias[n];
        #pragma unroll
        for (int i = 0; i < 8; ++i) {
            const int mb = m0 + (2 * i + wmi) * 16 + lq * 4;
            #pragma unroll
            for (int r = 0; r < 4; ++r)
                out[(size_t)(mb + r) * N + n] = acc[i][j][r] + bv;
        }
    }
}

// ---------------------------------------------------------------------------
// Fallback (small workspace): 128^2 m97-structure GEMM reading f32 X directly.
// ---------------------------------------------------------------------------
#define TM 128
#define TN 128
#define BK 32

__global__ void gemm_bt_f32(const float* __restrict__ Xf, const u16* __restrict__ Gt,
                            const float* __restrict__ bias, float* __restrict__ out) {
    constexpr int K = 4096, N = 4096;
    __shared__ __attribute__((aligned(16))) u16 As[TM * BK];
    __shared__ __attribute__((aligned(16))) u16 Bs[TN * BK];

    const int tid  = threadIdx.x;
    const int lane = tid & 63;
    const int w    = tid >> 6;
    const int m0   = blockIdx.y * TM;
    const int n0   = blockIdx.x * TN;
    const int wm   = (w >> 1) * 64;
    const int wn   = (w & 1) * 64;
    const int lr   = lane & 15;
    const int lk   = (lane >> 4) * 8;

    f32x4 acc[4][4] = {};

    const int srow   = tid >> 2;
    const int schunk = (tid & 3) * 8;
    const u16* grow0 = Gt + (size_t)(n0 + srow) * K + schunk;
    const u16* grow1 = Gt + (size_t)(n0 + 64 + srow) * K + schunk;
    u16* ldsB0 = &Bs[(tid & ~63) * 8];
    u16* ldsB1 = &Bs[(256 + (tid & ~63)) * 8];

    const float* xsrc = Xf + (size_t)(m0 + (tid >> 1)) * K + (tid & 1) * 16;
    u16* adst = &As[(tid >> 1) * BK + (tid & 1) * 16];

    for (int k0 = 0; k0 < K; k0 += BK) {
        __syncthreads();
        {
            f32x4 v0 = ((const f32x4*)(xsrc + k0))[0];
            f32x4 v1 = ((const f32x4*)(xsrc + k0))[1];
            f32x4 v2 = ((const f32x4*)(xsrc + k0))[2];
            f32x4 v3 = ((const f32x4*)(xsrc + k0))[3];
            bf16x8 w0, w1;
            #pragma unroll
            for (int j = 0; j < 4; ++j) {
                w0[j]     = (short)f2bf(v0[j]);
                w0[4 + j] = (short)f2bf(v1[j]);
                w1[j]     = (short)f2bf(v2[j]);
                w1[4 + j] = (short)f2bf(v3[j]);
            }
            *(bf16x8*)adst = w0;
            *(bf16x8*)(adst + 8) = w1;
        }
        async_load16(grow0 + k0, ldsB0);
        async_load16(grow1 + k0, ldsB1);
        __syncthreads();

        bf16x8 af[4], bg[4];
        #pragma unroll
        for (int i = 0; i < 4; ++i) {
            af[i] = *(const bf16x8*)(&As[(wm + i * 16 + lr) * BK + lk]);
            bg[i] = *(const bf16x8*)(&Bs[(wn + i * 16 + lr) * BK + lk]);
        }
        #pragma unroll
        for (int mt = 0; mt < 4; ++mt)
            #pragma unroll
            for (int nt = 0; nt < 4; ++nt)
                acc[mt][nt] = __builtin_amdgcn_mfma_f32_16x16x32_bf16(
                    af[mt], bg[nt], acc[mt][nt], 0, 0, 0);
    }

    #pragma unroll
    for (int nt = 0; nt < 4; ++nt) {
        const int n = n0 + wn + nt * 16 + lr;
        const float bv = bias[n];
        #pragma unroll
        for (int mt = 0; mt < 4; ++mt) {
            const int mbase = m0 + wm + mt * 16 + (lane >> 4) * 4;
            #pragma unroll
            for (int r = 0; r < 4; ++r) {
                out[(size_t)(mbase + r) * N + n] = acc[mt][nt][r] + bv;
            }
        }
    }
}

extern "C" void kernel_launch(void* const* d_in, const int* in_sizes, int n_in,
                              void* d_out, int out_size, void* d_ws, size_t ws_size,
                              hipStream_t stream) {
    const float* x    = (const float*)d_in[0];  // (8,1024,4096) f32
    const float* c0   = (const float*)d_in[1];  // [4096][128] f32 (flattened)
    const float* c1   = (const float*)d_in[2];  // [4096][1024] f32
    const float* c2   = (const float*)d_in[3];  // [4096][128] f32
    const float* bias = (const float*)d_in[4];
    float* out = (float*)d_out;

    const size_t GT_BYTES = (size_t)4096 * 4096 * sizeof(u16);   // 32 MB
    const size_t XB_BYTES = (size_t)8192 * 4096 * sizeof(u16);   // 64 MB
    u16* Gt = (u16*)d_ws;

    if (ws_size >= GT_BYTES + XB_BYTES) {
        // Stage transposed cores in the Xb region (overwritten later by conv_x;
        // same-stream serialization makes this safe): c1t 16MB, c0t 2MB, c2t 2MB.
        char* scratch = (char*)d_ws + GT_BYTES;
        float* c1t = (float*)scratch;
        float* c0t = (float*)(scratch + (size_t)16 * 1024 * 1024);
        float* c2t = (float*)(scratch + (size_t)18 * 1024 * 1024);

        transpose_f32<<<dim3(16, 64), 256, 0, stream>>>(c1, c1t, 1024);
        transpose_f32<<<dim3(2, 64), 256, 0, stream>>>(c0, c0t, 128);
        transpose_f32<<<dim3(2, 64), 256, 0, stream>>>(c2, c2t, 128);
        build_gt_t<<<1024, 256, 0, stream>>>(c0t, c1t, c2t, Gt);

        u16* Xb = (u16*)((char*)d_ws + GT_BYTES);
        conv_x<<<8192, 256, 0, stream>>>((const f32x4*)x, Xb, 8192 * 4096 / 4);

        static int attr_done = 0;
        if (!attr_done) {
            hipFuncSetAttribute(reinterpret_cast<const void*>(gemm_8ph),
                                hipFuncAttributeMaxDynamicSharedMemorySize, 131072);
            attr_done = 1;
        }
        gemm_8ph<<<dim3(16, 32), 512, 131072, stream>>>(Xb, Gt, bias, out);
    } else {
        build_gt<<<dim3(256, 16), 256, 0, stream>>>(c0, c1, c2, Gt);
        gemm_bt_f32<<<dim3(32, 64), 256, 0, stream>>>(x, Gt, bias, out);
    }
}